// Round 8
// baseline (291.034 us; speedup 1.0000x reference)
//
#include <hip/hip_runtime.h>
#include <math.h>

#define NPIX 3136   // 56*56
#define CCH  224
#define SCALING 0.17677669529663687f   // 32^-0.5
#define LOG2E 1.4426950408889634f
#define SCL2 (SCALING * LOG2E)         // folded into Q: logits in log2 domain

typedef _Float16 half8_t __attribute__((ext_vector_type(8)));
typedef _Float16 half4_t __attribute__((ext_vector_type(4)));
typedef _Float16 half2_t __attribute__((ext_vector_type(2)));
typedef float floatx4 __attribute__((ext_vector_type(4)));

__device__ __forceinline__ float exp2fast(float x) { return __builtin_amdgcn_exp2f(x); }

// XOR-swizzled LDS index (half units, 64-half rows): spreads row-aliased banks.
#define SWZ(r, c) ((((r) << 6)) | ((c) ^ (((r) & 7) << 3)))

// ---------------- helpers ----------------
__device__ __forceinline__ void blockReduce2(float& a, float& b, float* scratch) {
  #pragma unroll
  for (int off = 32; off > 0; off >>= 1) {
    a += __shfl_down(a, off);
    b += __shfl_down(b, off);
  }
  int wid = threadIdx.x >> 6, lane = threadIdx.x & 63;
  if (lane == 0) { scratch[wid * 2] = a; scratch[wid * 2 + 1] = b; }
  __syncthreads();
  if (threadIdx.x == 0) {
    float sa = 0.f, sb = 0.f;
    #pragma unroll
    for (int i = 0; i < 4; ++i) { sa += scratch[2 * i]; sb += scratch[2 * i + 1]; }
    scratch[0] = sa; scratch[1] = sb;
  }
  __syncthreads();
  a = scratch[0]; b = scratch[1];
}

// ---------------- prep: gating + instance norm + (fused) wcvt + lam ----------------
__global__ __launch_bounds__(256) void prep_kernel(const float* __restrict__ D,
                                                   const float* __restrict__ gn_w,
                                                   const float* __restrict__ gn_b,
                                                   _Float16* __restrict__ senh_h,
                                                   _Float16* __restrict__ Dh,
                                                   const float* __restrict__ wq,
                                                   const float* __restrict__ wk,
                                                   const float* __restrict__ wv,
                                                   _Float16* __restrict__ whq,
                                                   _Float16* __restrict__ whk,
                                                   _Float16* __restrict__ whv,
                                                   const float* __restrict__ lq1,
                                                   const float* __restrict__ lk1,
                                                   const float* __restrict__ lq2,
                                                   const float* __restrict__ lk2,
                                                   const float* __restrict__ lambda_init,
                                                   float* __restrict__ lam) {
  __shared__ float img[NPIX];
  __shared__ float xh[56];
  __shared__ float xw[56];
  __shared__ float rp[56][4];
  __shared__ float cp_[56][4];
  __shared__ float scratch[8];
  int bc = blockIdx.x;
  int c = bc % CCH;
  const float* src = D + (size_t)bc * NPIX;
  float4* img4 = (float4*)img;
  const float4* src4 = (const float4*)src;
  half4_t* dh4 = (half4_t*)(Dh + (size_t)bc * NPIX);
  for (int i = threadIdx.x; i < NPIX / 4; i += 256) {
    float4 v = src4[i];
    img4[i] = v;
    half4_t hv;
    hv[0] = (_Float16)v.x; hv[1] = (_Float16)v.y;
    hv[2] = (_Float16)v.z; hv[3] = (_Float16)v.w;
    dh4[i] = hv;
  }
  // fused weight conversion (62720 float4s over blocks 0..244)
  {
    int i = bc * 256 + threadIdx.x;
    const int NQ = 448 * 224 / 4, NV = 224 * 224 / 4;
    if (i < 2 * NQ + NV) {
      const float* wsrc; _Float16* wdst; int off;
      if (i < NQ) { wsrc = wq; wdst = whq; off = i; }
      else if (i < 2 * NQ) { wsrc = wk; wdst = whk; off = i - NQ; }
      else { wsrc = wv; wdst = whv; off = i - 2 * NQ; }
      float4 v = ((const float4*)wsrc)[off];
      half4_t h;
      h[0] = (_Float16)v.x; h[1] = (_Float16)v.y;
      h[2] = (_Float16)v.z; h[3] = (_Float16)v.w;
      ((half4_t*)wdst)[off] = h;
    }
  }
  __syncthreads();
  int t = threadIdx.x;
  if (t < 224) {
    int r = t >> 2, qq = t & 3;
    float s = 0.f;
    #pragma unroll 14
    for (int j = 0; j < 14; ++j) s += img[r * 56 + qq * 14 + j];
    rp[r][qq] = s;
  }
  __syncthreads();
  if (t < 224) {
    int cc = t >> 2, qq = t & 3;
    float s = 0.f;
    #pragma unroll 14
    for (int j = 0; j < 14; ++j) s += img[(qq * 14 + j) * 56 + cc];
    cp_[cc][qq] = s;
  }
  __syncthreads();
  if (t < 56) xh[t] = (rp[t][0] + rp[t][1] + rp[t][2] + rp[t][3]) * (1.f / 56.f);
  else if (t >= 64 && t < 120) {
    int cc = t - 64;
    xw[cc] = (cp_[cc][0] + cp_[cc][1] + cp_[cc][2] + cp_[cc][3]) * (1.f / 56.f);
  }
  __syncthreads();
  float sum = 0.f, ssq = 0.f;
  for (int i = threadIdx.x; i < NPIX; i += 256) {
    int y = i / 56, x = i - y * 56;
    float d = img[i];
    float tt = xh[y] + xw[x];
    float sg = 1.f / (1.f + __expf(-tt));
    float g = d * sg;
    img[i] = g;
    sum += g;
    ssq += g * g;
  }
  blockReduce2(sum, ssq, scratch);
  float mu = sum * (1.f / (float)NPIX);
  float var = ssq * (1.f / (float)NPIX) - mu * mu;
  float rstd = rsqrtf(var + 1e-5f);
  float a = gn_w[c] * rstd;
  float bb = gn_b[c] - mu * a;
  _Float16* dst = senh_h + (size_t)bc * NPIX;
  for (int i = threadIdx.x; i < NPIX; i += 256) dst[i] = (_Float16)fmaf(img[i], a, bb);
  // fused lam (block 0, wave 0)
  if (bc == 0 && t < 32) {
    float p1 = lq1[t] * lk1[t];
    float p2 = lq2[t] * lk2[t];
    #pragma unroll
    for (int off = 16; off > 0; off >>= 1) {
      p1 += __shfl_down(p1, off);
      p2 += __shfl_down(p2, off);
    }
    if (t == 0) {
      float d = expf(p1) - expf(p2);
      d = fminf(fmaxf(d, 0.f), 1.f);
      lam[0] = d + lambda_init[0];
    }
  }
}

// ---------------- fused QKV f16 MFMA GEMM ----------------
__global__ __launch_bounds__(256) void gemm_qkv_kernel(const _Float16* __restrict__ Whq,
                                                       const _Float16* __restrict__ Whk,
                                                       const _Float16* __restrict__ Whv,
                                                       const _Float16* __restrict__ senh_h,
                                                       const _Float16* __restrict__ Dh,
                                                       const float* __restrict__ bq,
                                                       const float* __restrict__ bk,
                                                       const float* __restrict__ bv,
                                                       _Float16* __restrict__ Qt,
                                                       _Float16* __restrict__ Kt,
                                                       _Float16* __restrict__ Vt,
                                                       const float* __restrict__ lamp) {
  __shared__ _Float16 Xs[2][64][40];
  __shared__ _Float16 Cs[64][72];
  int b = blockIdx.z;
  int sel = blockIdx.y;
  int mode, r0, M;
  const _Float16* Wh;
  const _Float16* Xb;
  const float* bias;
  _Float16* Y;
  if (sel < 7)       { mode = 1; r0 = sel * 64;        M = 448; Wh = Whq; Xb = senh_h; bias = bq; Y = Qt; }
  else if (sel < 14) { mode = 2; r0 = (sel - 7) * 64;  M = 448; Wh = Whk; Xb = Dh;     bias = bk; Y = Kt; }
  else               { mode = 0; r0 = (sel - 14) * 64; M = 224; Wh = Whv; Xb = Dh;     bias = bv; Y = Vt; }
  Xb += (size_t)b * CCH * NPIX;
  int n0 = blockIdx.x * 64;
  int tid = threadIdx.x;
  int w = tid >> 6, lane = tid & 63, q = lane & 15, g = lane >> 4;

  int wrow = r0 + w * 16 + q;
  if (wrow >= M) wrow = M - 1;
  half8_t wfrag[7];
  #pragma unroll
  for (int kc = 0; kc < 7; ++kc)
    wfrag[kc] = *(const half8_t*)&Wh[(size_t)wrow * 224 + kc * 32 + g * 8];

  floatx4 acc[4];
  #pragma unroll
  for (int t = 0; t < 4; ++t)
    #pragma unroll
    for (int r = 0; r < 4; ++r) acc[t][r] = 0.f;

  int cp = tid & 15, ng = tid >> 4;
  {
    const _Float16* x0 = Xb + (size_t)(2 * cp) * NPIX + n0 + ng * 4;
    half4_t xa = *(const half4_t*)x0;
    half4_t xb = *(const half4_t*)(x0 + NPIX);
    #pragma unroll
    for (int j = 0; j < 4; ++j) {
      half2_t hw; hw[0] = xa[j]; hw[1] = xb[j];
      *(half2_t*)&Xs[0][ng * 4 + j][2 * cp] = hw;
    }
  }
  __syncthreads();
  #pragma unroll
  for (int kc = 0; kc < 7; ++kc) {
    int cur = kc & 1;
    half4_t xa, xb;
    if (kc < 6) {
      const _Float16* x0 = Xb + (size_t)((kc + 1) * 32 + 2 * cp) * NPIX + n0 + ng * 4;
      xa = *(const half4_t*)x0;
      xb = *(const half4_t*)(x0 + NPIX);
    }
    #pragma unroll
    for (int t = 0; t < 4; ++t) {
      half8_t xfrag = *(const half8_t*)&Xs[cur][16 * t + q][g * 8];
      acc[t] = __builtin_amdgcn_mfma_f32_16x16x32_f16(wfrag[kc], xfrag, acc[t], 0, 0, 0);
    }
    if (kc < 6) {
      #pragma unroll
      for (int j = 0; j < 4; ++j) {
        half2_t hw; hw[0] = xa[j]; hw[1] = xb[j];
        *(half2_t*)&Xs[cur ^ 1][ng * 4 + j][2 * cp] = hw;
      }
    }
    __syncthreads();
  }

  float lamv = (mode == 1) ? lamp[0] : 0.f;
  #pragma unroll
  for (int t = 0; t < 4; ++t) {
    #pragma unroll
    for (int r = 0; r < 4; ++r) {
      int m = w * 16 + 4 * g + r;
      int n = 16 * t + q;
      int gm = r0 + m;
      float v = 0.f;
      if (gm < M) {
        v = acc[t][r] + bias[gm];
        if (mode == 1) v *= (gm < CCH) ? SCL2 : (-lamv * SCL2);
      }
      Cs[m][n] = (_Float16)v;
    }
  }
  __syncthreads();

  if (mode == 0) {
    int row = tid >> 2, oct = tid & 3;
    if (r0 + row < M) {
      half8_t u0 = *(half8_t*)&Cs[row][oct * 16];
      half8_t u1 = *(half8_t*)&Cs[row][oct * 16 + 8];
      _Float16* dst = Y + ((size_t)b * CCH + r0 + row) * NPIX + n0 + oct * 16;
      *(half8_t*)dst = u0;
      *(half8_t*)(dst + 8) = u1;
    }
  } else {
    int n = tid & 63, quarter = tid >> 6;
    int vbase = r0 + quarter * 16;
    int chunk = vbase >= CCH;
    int ch_in = vbase - chunk * CCH;
    int hh = ch_in >> 5;
    int dstart = chunk * 32 + (ch_in & 31);
    _Float16 tmp[16];
    #pragma unroll
    for (int i = 0; i < 16; ++i) tmp[i] = Cs[quarter * 16 + i][n];
    _Float16* dst = Y + (((size_t)b * 7 + hh) * NPIX + (n0 + n)) * 64 + dstart;
    *(half8_t*)dst = *(half8_t*)&tmp[0];
    *(half8_t*)(dst + 8) = *(half8_t*)&tmp[8];
  }
}

// ---------------- MFMA flash attention: split-K x4, exp2, defer-max, XOR-swz LDS ----------------
__global__ __launch_bounds__(256) void attn_part_kernel(const _Float16* __restrict__ Qt,
                                                        const _Float16* __restrict__ Kt,
                                                        const _Float16* __restrict__ Vt,
                                                        _Float16* __restrict__ Opart,
                                                        float2* __restrict__ ml2,
                                                        float* __restrict__ wx_raw) {
  __shared__ _Float16 K_lds[2][4096];   // [64][64] swizzled
  __shared__ _Float16 V_lds[2][2048];   // [32][64] swizzled
  __shared__ _Float16 P_lds[4096];      // [64][64] swizzled

  int orig = blockIdx.x;
  if (orig == 0 && threadIdx.x < 448) wx_raw[threadIdx.x] = 0.f;  // zero for merge atomics
  int wg = (orig & 7) * 343 + (orig >> 3);   // 2744 = 8*343 bijective
  int qt = wg % 49;
  int rest = wg / 49;
  int seg = rest & 3, bh = rest >> 2;
  int h = bh % 7, b = bh / 7;
  int t0 = (seg == 0) ? 0 : (12 * seg + 1);
  int nt = seg ? 12 : 13;

  int tid = threadIdx.x;
  int w = tid >> 6, lane = tid & 63;
  int q = lane & 15, g = lane >> 4;
  int nq = qt * 64 + w * 16 + q;

  const _Float16* Qb = Qt + ((size_t)(b * 7 + h) * NPIX + nq) * 64;
  const _Float16* Kb = Kt + (size_t)(b * 7 + h) * NPIX * 64;
  const _Float16* Vb = Vt + ((size_t)b * CCH + h * 32) * NPIX;

  half8_t qv[2];
  qv[0] = *(const half8_t*)(Qb + g * 8);
  qv[1] = *(const half8_t*)(Qb + 32 + g * 8);

  floatx4 oacc[2];
  #pragma unroll
  for (int dt = 0; dt < 2; ++dt)
    #pragma unroll
    for (int r = 0; r < 4; ++r) oacc[dt][r] = 0.f;
  float mrun = -INFINITY, lrun = 0.f;   // lrun is PER-LANE; reduced once at end

  int kkey = tid >> 2, koct = (tid & 3) * 16;
  const _Float16* ksrc = Kb + ((size_t)t0 * 64 + kkey) * 64 + koct;
  int vd = tid >> 3, voff = (tid & 7) * 8;
  const _Float16* vsrc = Vb + (size_t)vd * NPIX + t0 * 64 + voff;

  half8_t kr0, kr1, vr;
  kr0 = *(const half8_t*)(ksrc);
  kr1 = *(const half8_t*)(ksrc + 8);
  vr = *(const half8_t*)(vsrc);
  *(half8_t*)&K_lds[0][SWZ(kkey, koct)] = kr0;
  *(half8_t*)&K_lds[0][SWZ(kkey, koct + 8)] = kr1;
  *(half8_t*)&V_lds[0][SWZ(vd, voff)] = vr;
  __syncthreads();

  for (int kc = 0; kc < nt; ++kc) {
    int cur = kc & 1;
    if (kc < nt - 1) {
      size_t m0 = (size_t)(kc + 1) * 64;
      kr0 = *(const half8_t*)(ksrc + m0 * 64);
      kr1 = *(const half8_t*)(ksrc + m0 * 64 + 8);
      vr = *(const half8_t*)(vsrc + m0);
    }

    // ---- QK^T ----
    floatx4 sacc[4];
    #pragma unroll
    for (int t = 0; t < 4; ++t)
      #pragma unroll
      for (int r = 0; r < 4; ++r) sacc[t][r] = 0.f;
    #pragma unroll
    for (int t = 0; t < 4; ++t) {
      #pragma unroll
      for (int c = 0; c < 2; ++c) {
        half8_t ka = *(const half8_t*)&K_lds[cur][SWZ(t * 16 + q, c * 32 + g * 8)];
        sacc[t] = __builtin_amdgcn_mfma_f32_16x16x32_f16(ka, qv[c], sacc[t], 0, 0, 0);
      }
    }

    // ---- online softmax, defer-max (log2 domain) ----
    float tmax = fmaxf(fmaxf(sacc[0][0], sacc[0][1]), fmaxf(sacc[0][2], sacc[0][3]));
    #pragma unroll
    for (int t = 1; t < 4; ++t)
      tmax = fmaxf(tmax, fmaxf(fmaxf(sacc[t][0], sacc[t][1]), fmaxf(sacc[t][2], sacc[t][3])));
    tmax = fmaxf(tmax, __shfl_xor(tmax, 16));
    tmax = fmaxf(tmax, __shfl_xor(tmax, 32));
    if (__any(tmax > mrun + 8.f)) {
      float mnew = fmaxf(mrun, tmax);
      float corr = exp2fast(mrun - mnew);
      lrun *= corr;
      #pragma unroll
      for (int dt = 0; dt < 2; ++dt)
        #pragma unroll
        for (int r = 0; r < 4; ++r) oacc[dt][r] *= corr;
      mrun = mnew;
    }
    #pragma unroll
    for (int t = 0; t < 4; ++t)
      #pragma unroll
      for (int r = 0; r < 4; ++r) {
        float p = exp2fast(sacc[t][r] - mrun);
        sacc[t][r] = p;
        lrun += p;
      }

    // ---- P -> f16 -> per-wave LDS rows ----
    #pragma unroll
    for (int t = 0; t < 4; ++t) {
      half4_t ph;
      ph[0] = (_Float16)sacc[t][0];
      ph[1] = (_Float16)sacc[t][1];
      ph[2] = (_Float16)sacc[t][2];
      ph[3] = (_Float16)sacc[t][3];
      *(half4_t*)&P_lds[SWZ(w * 16 + q, t * 16 + g * 4)] = ph;
    }

    // ---- PV ----
    #pragma unroll
    for (int dt = 0; dt < 2; ++dt) {
      #pragma unroll
      for (int c = 0; c < 2; ++c) {
        half8_t va = *(const half8_t*)&V_lds[cur][SWZ(dt * 16 + q, c * 32 + g * 8)];
        half8_t pb = *(const half8_t*)&P_lds[SWZ(w * 16 + q, c * 32 + g * 8)];
        oacc[dt] = __builtin_amdgcn_mfma_f32_16x16x32_f16(va, pb, oacc[dt], 0, 0, 0);
      }
    }

    if (kc < nt - 1) {
      *(half8_t*)&K_lds[cur ^ 1][SWZ(kkey, koct)] = kr0;
      *(half8_t*)&K_lds[cur ^ 1][SWZ(kkey, koct + 8)] = kr1;
      *(half8_t*)&V_lds[cur ^ 1][SWZ(vd, voff)] = vr;
    }
    __syncthreads();
  }

  // deferred l reduction (cross g-groups)
  lrun += __shfl_xor(lrun, 16);
  lrun += __shfl_xor(lrun, 32);

  // ---- write partials ----
  size_t pbase = (((size_t)bh * 4 + seg) * 49 + qt);
  float* out_lds = (float*)&K_lds[0][0];   // 32*68*4 = 8704B
  #pragma unroll
  for (int dt = 0; dt < 2; ++dt)
    #pragma unroll
    for (int r = 0; r < 4; ++r) {
      int d = dt * 16 + g * 4 + r;
      out_lds[d * 68 + w * 16 + q] = oacc[dt][r];
    }
  if (lane < 16) ml2[pbase * 64 + w * 16 + lane] = make_float2(mrun, lrun);
  __syncthreads();
  {
    int d = tid >> 3;
    int i8 = (tid & 7) << 3;
    half8_t hv;
    #pragma unroll
    for (int j = 0; j < 8; ++j) hv[j] = (_Float16)out_lds[d * 68 + i8 + j];
    *(half8_t*)(Opart + pbase * 2048 + d * 64 + i8) = hv;
  }
}

// ---------------- merge 4 key-segments -> attno f16; fused channel sums ----------------
__global__ __launch_bounds__(256) void merge_kernel(const _Float16* __restrict__ Opart,
                                                    const float2* __restrict__ ml2,
                                                    _Float16* __restrict__ attno,
                                                    float* __restrict__ wx_raw) {
  int blk = blockIdx.x;          // 686: bh*49 + qt
  int qt = blk % 49, bh = blk / 49;
  int b = bh / 7, h = bh % 7;
  int tid = threadIdx.x, q = tid & 63, dg = tid >> 6;
  size_t p0 = (size_t)bh * 4 * 49 + qt;
  float2 s0 = ml2[(p0 + 0 * 49) * 64 + q];
  float2 s1 = ml2[(p0 + 1 * 49) * 64 + q];
  float2 s2 = ml2[(p0 + 2 * 49) * 64 + q];
  float2 s3 = ml2[(p0 + 3 * 49) * 64 + q];
  float m = fmaxf(fmaxf(s0.x, s1.x), fmaxf(s2.x, s3.x));
  float w0 = exp2fast(s0.x - m), w1 = exp2fast(s1.x - m);
  float w2 = exp2fast(s2.x - m), w3 = exp2fast(s3.x - m);
  float inv = 1.f / (s0.y * w0 + s1.y * w1 + s2.y * w2 + s3.y * w3);
  float osum[8];
  #pragma unroll
  for (int i = 0; i < 8; ++i) {
    int d = dg * 8 + i;
    float o = ((float)Opart[(p0 + 0 * 49) * 2048 + d * 64 + q] * w0 +
               (float)Opart[(p0 + 1 * 49) * 2048 + d * 64 + q] * w1 +
               (float)Opart[(p0 + 2 * 49) * 2048 + d * 64 + q] * w2 +
               (float)Opart[(p0 + 3 * 49) * 2048 + d * 64 + q] * w3) * inv;
    attno[((size_t)b * CCH + h * 32 + d) * NPIX + qt * 64 + q] = (_Float16)o;
    osum[i] = o;
  }
  #pragma unroll
  for (int i = 0; i < 8; ++i) {
    #pragma unroll
    for (int off = 32; off > 0; off >>= 1) osum[i] += __shfl_xor(osum[i], off);
  }
  if ((tid & 63) == 0) {
    #pragma unroll
    for (int i = 0; i < 8; ++i)
      atomicAdd(&wx_raw[b * CCH + h * 32 + dg * 8 + i], osum[i]);
  }
}

// ---------------- fused tail: weff (in-LDS) + M maps (+halo) + 3x3 gather + sigmoid ----------------
// grid (14, 2): each block owns 224 pixels (4 image rows), computes M over +-57 halo.
__global__ __launch_bounds__(256) void tail_kernel(const _Float16* __restrict__ attno,
                                                   const float* __restrict__ wx_raw,
                                                   const float* __restrict__ wo,
                                                   const float* __restrict__ w3,
                                                   const float* __restrict__ b3,
                                                   const float* __restrict__ bo,
                                                   float* __restrict__ dout) {
  __shared__ float wsh[CCH];
  __shared__ float weff_s[2016];
  __shared__ float Msh[9][344];
  __shared__ float scratch[8];
  int b = blockIdx.y, tile = blockIdx.x;
  int t = threadIdx.x;
  if (t < CCH) {
    float mean = wx_raw[b * CCH + t] * (1.f / (float)NPIX);
    wsh[t] = wo[t] / (1.f + expf(-mean));
  }
  __syncthreads();
  float bf = (t < CCH) ? wsh[t] * b3[t] : 0.f;
  float dummy = 0.f;
  blockReduce2(bf, dummy, scratch);
  float beff = bf + bo[0];
  // weff into LDS
  for (int rem = t; rem < 2016; rem += 256) {
    float a0 = 0.f, a1 = 0.f, a2 = 0.f, a3 = 0.f;
    for (int c = 0; c < CCH; c += 4) {
      a0 = fmaf(wsh[c + 0], w3[(size_t)(c + 0) * 2016 + rem], a0);
      a1 = fmaf(wsh[c + 1], w3[(size_t)(c + 1) * 2016 + rem], a1);
      a2 = fmaf(wsh[c + 2], w3[(size_t)(c + 2) * 2016 + rem], a2);
      a3 = fmaf(wsh[c + 3], w3[(size_t)(c + 3) * 2016 + rem], a3);
    }
    weff_s[rem] = (a0 + a1) + (a2 + a3);
  }
  __syncthreads();
  // M maps over halo range [tile*224-57, tile*224+224+57)
  int p_lo = tile * 224 - 57;
  const _Float16* A = attno + (size_t)b * CCH * NPIX;
  for (int j = t; j < 338; j += 256) {
    int px = p_lo + j;
    float m[9];
    #pragma unroll
    for (int k = 0; k < 9; ++k) m[k] = 0.f;
    if (px >= 0 && px < NPIX) {
      for (int c = 0; c < CCH; ++c) {
        float a = (float)A[(size_t)c * NPIX + px];
        const float* wp = &weff_s[c * 9];
        #pragma unroll
        for (int k = 0; k < 9; ++k) m[k] = fmaf(a, wp[k], m[k]);
      }
    }
    #pragma unroll
    for (int k = 0; k < 9; ++k) Msh[k][j] = m[k];
  }
  __syncthreads();
  // final 3x3 gather + sigmoid for own 224 pixels
  if (t < 224) {
    int px = tile * 224 + t;
    int y = px / 56, x = px - y * 56;
    float s = 0.f;
    #pragma unroll
    for (int ky = 0; ky < 3; ++ky) {
      int yy = y + ky - 1;
      if (yy < 0 || yy >= 56) continue;
      #pragma unroll
      for (int kx = 0; kx < 3; ++kx) {
        int xx = x + kx - 1;
        if (xx < 0 || xx >= 56) continue;
        s += Msh[ky * 3 + kx][yy * 56 + xx - p_lo];
      }
    }
    float v = s + beff;
    dout[b * NPIX + px] = 1.f / (1.f + expf(-v));
  }
}

extern "C" void kernel_launch(void* const* d_in, const int* in_sizes, int n_in,
                              void* d_out, int out_size, void* d_ws, size_t ws_size,
                              hipStream_t stream) {
  (void)in_sizes; (void)n_in; (void)out_size; (void)ws_size;
  const float* D = (const float*)d_in[0];
  const float* wq = (const float*)d_in[1];
  const float* bq = (const float*)d_in[2];
  const float* wk = (const float*)d_in[3];
  const float* bk = (const float*)d_in[4];
  const float* wv = (const float*)d_in[5];
  const float* bv = (const float*)d_in[6];
  const float* gn_w = (const float*)d_in[7];
  const float* gn_b = (const float*)d_in[8];
  const float* lambda_init = (const float*)d_in[9];
  const float* lq1 = (const float*)d_in[10];
  const float* lk1 = (const float*)d_in[11];
  const float* lq2 = (const float*)d_in[12];
  const float* lk2 = (const float*)d_in[13];
  const float* w3 = (const float*)d_in[14];
  const float* b3 = (const float*)d_in[15];
  const float* wo = (const float*)d_in[16];
  const float* bo = (const float*)d_in[17];

  char* p = (char*)d_ws;
  _Float16* Dh = (_Float16*)p;          p += 2809856;
  _Float16* senh_h = (_Float16*)p;      p += 2809856;
  _Float16* Whq = (_Float16*)p;         p += 200704;
  _Float16* Whk = (_Float16*)p;         p += 200704;
  _Float16* Whv = (_Float16*)p;         p += 100352;
  _Float16* Qt = (_Float16*)p;          p += 5619712;
  _Float16* Kt = (_Float16*)p;          p += 5619712;
  _Float16* Vt = (_Float16*)p;          p += 2809856;
  _Float16* Opart = (_Float16*)p;       p += 11239424;   // 14*4*49*2048*2
  float2* ml2 = (float2*)p;             p += 1404928;    // 14*4*49*64*8
  _Float16* attno = (_Float16*)p;       p += 2809856;    // f16 now
  float* wx_raw = (float*)p;            p += 1792;
  float* lam = (float*)p;               p += 64;

  prep_kernel<<<448, 256, 0, stream>>>(D, gn_w, gn_b, senh_h, Dh,
                                       wq, wk, wv, Whq, Whk, Whv,
                                       lq1, lk1, lq2, lk2, lambda_init, lam);
  gemm_qkv_kernel<<<dim3(49, 18, 2), 256, 0, stream>>>(Whq, Whk, Whv, senh_h, Dh,
                                                       bq, bk, bv, Qt, Kt, Vt, lam);
  attn_part_kernel<<<2744, 256, 0, stream>>>(Qt, Kt, Vt, Opart, ml2, wx_raw);
  merge_kernel<<<686, 256, 0, stream>>>(Opart, ml2, attno, wx_raw);
  tail_kernel<<<dim3(14, 2), 256, 0, stream>>>(attno, wx_raw, wo, w3, b3, bo, (float*)d_out);
}

// Round 10
// 219.417 us; speedup vs baseline: 1.3264x; 1.3264x over previous
//
#include <hip/hip_runtime.h>
#include <math.h>

#define NPIX 3136   // 56*56
#define CCH  224
#define SCALING 0.17677669529663687f   // 32^-0.5
#define LOG2E 1.4426950408889634f
#define SCL2 (SCALING * LOG2E)         // folded into Q: logits in log2 domain

typedef _Float16 half8_t __attribute__((ext_vector_type(8)));
typedef _Float16 half4_t __attribute__((ext_vector_type(4)));
typedef _Float16 half2_t __attribute__((ext_vector_type(2)));
typedef float floatx4 __attribute__((ext_vector_type(4)));

__device__ __forceinline__ float exp2fast(float x) { return __builtin_amdgcn_exp2f(x); }

// XOR-swizzled LDS index (half units, 64-half rows): spreads row-aliased banks.
#define SWZ(r, c) ((((r) << 6)) | ((c) ^ (((r) & 7) << 3)))

// ---------------- helpers ----------------
__device__ __forceinline__ void blockReduce2(float& a, float& b, float* scratch) {
  #pragma unroll
  for (int off = 32; off > 0; off >>= 1) {
    a += __shfl_down(a, off);
    b += __shfl_down(b, off);
  }
  int wid = threadIdx.x >> 6, lane = threadIdx.x & 63;
  if (lane == 0) { scratch[wid * 2] = a; scratch[wid * 2 + 1] = b; }
  __syncthreads();
  if (threadIdx.x == 0) {
    float sa = 0.f, sb = 0.f;
    #pragma unroll
    for (int i = 0; i < 4; ++i) { sa += scratch[2 * i]; sb += scratch[2 * i + 1]; }
    scratch[0] = sa; scratch[1] = sb;
  }
  __syncthreads();
  a = scratch[0]; b = scratch[1];
}

// ---------------- prep: gating + instance norm + (fused) wcvt + lam ----------------
__global__ __launch_bounds__(256) void prep_kernel(const float* __restrict__ D,
                                                   const float* __restrict__ gn_w,
                                                   const float* __restrict__ gn_b,
                                                   _Float16* __restrict__ senh_h,
                                                   _Float16* __restrict__ Dh,
                                                   const float* __restrict__ wq,
                                                   const float* __restrict__ wk,
                                                   const float* __restrict__ wv,
                                                   _Float16* __restrict__ whq,
                                                   _Float16* __restrict__ whk,
                                                   _Float16* __restrict__ whv,
                                                   const float* __restrict__ lq1,
                                                   const float* __restrict__ lk1,
                                                   const float* __restrict__ lq2,
                                                   const float* __restrict__ lk2,
                                                   const float* __restrict__ lambda_init,
                                                   float* __restrict__ lam) {
  __shared__ float img[NPIX];
  __shared__ float xh[56];
  __shared__ float xw[56];
  __shared__ float rp[56][4];
  __shared__ float cp_[56][4];
  __shared__ float scratch[8];
  int bc = blockIdx.x;
  int c = bc % CCH;
  const float* src = D + (size_t)bc * NPIX;
  float4* img4 = (float4*)img;
  const float4* src4 = (const float4*)src;
  half4_t* dh4 = (half4_t*)(Dh + (size_t)bc * NPIX);
  for (int i = threadIdx.x; i < NPIX / 4; i += 256) {
    float4 v = src4[i];
    img4[i] = v;
    half4_t hv;
    hv[0] = (_Float16)v.x; hv[1] = (_Float16)v.y;
    hv[2] = (_Float16)v.z; hv[3] = (_Float16)v.w;
    dh4[i] = hv;
  }
  // fused weight conversion (62720 float4s over blocks 0..244)
  {
    int i = bc * 256 + threadIdx.x;
    const int NQ = 448 * 224 / 4, NV = 224 * 224 / 4;
    if (i < 2 * NQ + NV) {
      const float* wsrc; _Float16* wdst; int off;
      if (i < NQ) { wsrc = wq; wdst = whq; off = i; }
      else if (i < 2 * NQ) { wsrc = wk; wdst = whk; off = i - NQ; }
      else { wsrc = wv; wdst = whv; off = i - 2 * NQ; }
      float4 v = ((const float4*)wsrc)[off];
      half4_t h;
      h[0] = (_Float16)v.x; h[1] = (_Float16)v.y;
      h[2] = (_Float16)v.z; h[3] = (_Float16)v.w;
      ((half4_t*)wdst)[off] = h;
    }
  }
  __syncthreads();
  int t = threadIdx.x;
  if (t < 224) {
    int r = t >> 2, qq = t & 3;
    float s = 0.f;
    #pragma unroll 14
    for (int j = 0; j < 14; ++j) s += img[r * 56 + qq * 14 + j];
    rp[r][qq] = s;
  }
  __syncthreads();
  if (t < 224) {
    int cc = t >> 2, qq = t & 3;
    float s = 0.f;
    #pragma unroll 14
    for (int j = 0; j < 14; ++j) s += img[(qq * 14 + j) * 56 + cc];
    cp_[cc][qq] = s;
  }
  __syncthreads();
  if (t < 56) xh[t] = (rp[t][0] + rp[t][1] + rp[t][2] + rp[t][3]) * (1.f / 56.f);
  else if (t >= 64 && t < 120) {
    int cc = t - 64;
    xw[cc] = (cp_[cc][0] + cp_[cc][1] + cp_[cc][2] + cp_[cc][3]) * (1.f / 56.f);
  }
  __syncthreads();
  float sum = 0.f, ssq = 0.f;
  for (int i = threadIdx.x; i < NPIX; i += 256) {
    int y = i / 56, x = i - y * 56;
    float d = img[i];
    float tt = xh[y] + xw[x];
    float sg = 1.f / (1.f + __expf(-tt));
    float g = d * sg;
    img[i] = g;
    sum += g;
    ssq += g * g;
  }
  blockReduce2(sum, ssq, scratch);
  float mu = sum * (1.f / (float)NPIX);
  float var = ssq * (1.f / (float)NPIX) - mu * mu;
  float rstd = rsqrtf(var + 1e-5f);
  float a = gn_w[c] * rstd;
  float bb = gn_b[c] - mu * a;
  _Float16* dst = senh_h + (size_t)bc * NPIX;
  for (int i = threadIdx.x; i < NPIX; i += 256) dst[i] = (_Float16)fmaf(img[i], a, bb);
  // fused lam (block 0, wave 0)
  if (bc == 0 && t < 32) {
    float p1 = lq1[t] * lk1[t];
    float p2 = lq2[t] * lk2[t];
    #pragma unroll
    for (int off = 16; off > 0; off >>= 1) {
      p1 += __shfl_down(p1, off);
      p2 += __shfl_down(p2, off);
    }
    if (t == 0) {
      float d = expf(p1) - expf(p2);
      d = fminf(fmaxf(d, 0.f), 1.f);
      lam[0] = d + lambda_init[0];
    }
  }
}

// ---------------- fused QKV f16 MFMA GEMM ----------------
__global__ __launch_bounds__(256) void gemm_qkv_kernel(const _Float16* __restrict__ Whq,
                                                       const _Float16* __restrict__ Whk,
                                                       const _Float16* __restrict__ Whv,
                                                       const _Float16* __restrict__ senh_h,
                                                       const _Float16* __restrict__ Dh,
                                                       const float* __restrict__ bq,
                                                       const float* __restrict__ bk,
                                                       const float* __restrict__ bv,
                                                       _Float16* __restrict__ Qt,
                                                       _Float16* __restrict__ Kt,
                                                       _Float16* __restrict__ Vt,
                                                       const float* __restrict__ lamp) {
  __shared__ _Float16 Xs[2][64][40];
  __shared__ _Float16 Cs[64][72];
  int b = blockIdx.z;
  int sel = blockIdx.y;
  int mode, r0, M;
  const _Float16* Wh;
  const _Float16* Xb;
  const float* bias;
  _Float16* Y;
  if (sel < 7)       { mode = 1; r0 = sel * 64;        M = 448; Wh = Whq; Xb = senh_h; bias = bq; Y = Qt; }
  else if (sel < 14) { mode = 2; r0 = (sel - 7) * 64;  M = 448; Wh = Whk; Xb = Dh;     bias = bk; Y = Kt; }
  else               { mode = 0; r0 = (sel - 14) * 64; M = 224; Wh = Whv; Xb = Dh;     bias = bv; Y = Vt; }
  Xb += (size_t)b * CCH * NPIX;
  int n0 = blockIdx.x * 64;
  int tid = threadIdx.x;
  int w = tid >> 6, lane = tid & 63, q = lane & 15, g = lane >> 4;

  int wrow = r0 + w * 16 + q;
  if (wrow >= M) wrow = M - 1;
  half8_t wfrag[7];
  #pragma unroll
  for (int kc = 0; kc < 7; ++kc)
    wfrag[kc] = *(const half8_t*)&Wh[(size_t)wrow * 224 + kc * 32 + g * 8];

  floatx4 acc[4];
  #pragma unroll
  for (int t = 0; t < 4; ++t)
    #pragma unroll
    for (int r = 0; r < 4; ++r) acc[t][r] = 0.f;

  int cp = tid & 15, ng = tid >> 4;
  {
    const _Float16* x0 = Xb + (size_t)(2 * cp) * NPIX + n0 + ng * 4;
    half4_t xa = *(const half4_t*)x0;
    half4_t xb = *(const half4_t*)(x0 + NPIX);
    #pragma unroll
    for (int j = 0; j < 4; ++j) {
      half2_t hw; hw[0] = xa[j]; hw[1] = xb[j];
      *(half2_t*)&Xs[0][ng * 4 + j][2 * cp] = hw;
    }
  }
  __syncthreads();
  #pragma unroll
  for (int kc = 0; kc < 7; ++kc) {
    int cur = kc & 1;
    half4_t xa, xb;
    if (kc < 6) {
      const _Float16* x0 = Xb + (size_t)((kc + 1) * 32 + 2 * cp) * NPIX + n0 + ng * 4;
      xa = *(const half4_t*)x0;
      xb = *(const half4_t*)(x0 + NPIX);
    }
    #pragma unroll
    for (int t = 0; t < 4; ++t) {
      half8_t xfrag = *(const half8_t*)&Xs[cur][16 * t + q][g * 8];
      acc[t] = __builtin_amdgcn_mfma_f32_16x16x32_f16(wfrag[kc], xfrag, acc[t], 0, 0, 0);
    }
    if (kc < 6) {
      #pragma unroll
      for (int j = 0; j < 4; ++j) {
        half2_t hw; hw[0] = xa[j]; hw[1] = xb[j];
        *(half2_t*)&Xs[cur ^ 1][ng * 4 + j][2 * cp] = hw;
      }
    }
    __syncthreads();
  }

  float lamv = (mode == 1) ? lamp[0] : 0.f;
  #pragma unroll
  for (int t = 0; t < 4; ++t) {
    #pragma unroll
    for (int r = 0; r < 4; ++r) {
      int m = w * 16 + 4 * g + r;
      int n = 16 * t + q;
      int gm = r0 + m;
      float v = 0.f;
      if (gm < M) {
        v = acc[t][r] + bias[gm];
        if (mode == 1) v *= (gm < CCH) ? SCL2 : (-lamv * SCL2);
      }
      Cs[m][n] = (_Float16)v;
    }
  }
  __syncthreads();

  if (mode == 0) {
    int row = tid >> 2, oct = tid & 3;
    if (r0 + row < M) {
      half8_t u0 = *(half8_t*)&Cs[row][oct * 16];
      half8_t u1 = *(half8_t*)&Cs[row][oct * 16 + 8];
      _Float16* dst = Y + ((size_t)b * CCH + r0 + row) * NPIX + n0 + oct * 16;
      *(half8_t*)dst = u0;
      *(half8_t*)(dst + 8) = u1;
    }
  } else {
    int n = tid & 63, quarter = tid >> 6;
    int vbase = r0 + quarter * 16;
    int chunk = vbase >= CCH;
    int ch_in = vbase - chunk * CCH;
    int hh = ch_in >> 5;
    int dstart = chunk * 32 + (ch_in & 31);
    _Float16 tmp[16];
    #pragma unroll
    for (int i = 0; i < 16; ++i) tmp[i] = Cs[quarter * 16 + i][n];
    _Float16* dst = Y + (((size_t)b * 7 + hh) * NPIX + (n0 + n)) * 64 + dstart;
    *(half8_t*)dst = *(half8_t*)&tmp[0];
    *(half8_t*)(dst + 8) = *(half8_t*)&tmp[8];
  }
}

// ---------------- MFMA flash attention: split-K x4, exp2, defer-max, XOR-swz LDS ----------------
__global__ __launch_bounds__(256) void attn_part_kernel(const _Float16* __restrict__ Qt,
                                                        const _Float16* __restrict__ Kt,
                                                        const _Float16* __restrict__ Vt,
                                                        _Float16* __restrict__ Opart,
                                                        float2* __restrict__ ml2,
                                                        float* __restrict__ wx_raw) {
  __shared__ _Float16 K_lds[2][4096];   // [64][64] swizzled
  __shared__ _Float16 V_lds[2][2048];   // [32][64] swizzled
  __shared__ _Float16 P_lds[4096];      // [64][64] swizzled

  int orig = blockIdx.x;
  if (orig == 0 && threadIdx.x < 448) wx_raw[threadIdx.x] = 0.f;  // zero for merge atomics
  int wg = (orig & 7) * 343 + (orig >> 3);   // 2744 = 8*343 bijective
  int qt = wg % 49;
  int rest = wg / 49;
  int seg = rest & 3, bh = rest >> 2;
  int h = bh % 7, b = bh / 7;
  int t0 = (seg == 0) ? 0 : (12 * seg + 1);
  int nt = seg ? 12 : 13;

  int tid = threadIdx.x;
  int w = tid >> 6, lane = tid & 63;
  int q = lane & 15, g = lane >> 4;
  int nq = qt * 64 + w * 16 + q;

  const _Float16* Qb = Qt + ((size_t)(b * 7 + h) * NPIX + nq) * 64;
  const _Float16* Kb = Kt + (size_t)(b * 7 + h) * NPIX * 64;
  const _Float16* Vb = Vt + ((size_t)b * CCH + h * 32) * NPIX;

  half8_t qv[2];
  qv[0] = *(const half8_t*)(Qb + g * 8);
  qv[1] = *(const half8_t*)(Qb + 32 + g * 8);

  floatx4 oacc[2];
  #pragma unroll
  for (int dt = 0; dt < 2; ++dt)
    #pragma unroll
    for (int r = 0; r < 4; ++r) oacc[dt][r] = 0.f;
  float mrun = -INFINITY, lrun = 0.f;   // lrun is PER-LANE; reduced once at end

  int kkey = tid >> 2, koct = (tid & 3) * 16;
  const _Float16* ksrc = Kb + ((size_t)t0 * 64 + kkey) * 64 + koct;
  int vd = tid >> 3, voff = (tid & 7) * 8;
  const _Float16* vsrc = Vb + (size_t)vd * NPIX + t0 * 64 + voff;

  half8_t kr0, kr1, vr;
  kr0 = *(const half8_t*)(ksrc);
  kr1 = *(const half8_t*)(ksrc + 8);
  vr = *(const half8_t*)(vsrc);
  *(half8_t*)&K_lds[0][SWZ(kkey, koct)] = kr0;
  *(half8_t*)&K_lds[0][SWZ(kkey, koct + 8)] = kr1;
  *(half8_t*)&V_lds[0][SWZ(vd, voff)] = vr;
  __syncthreads();

  for (int kc = 0; kc < nt; ++kc) {
    int cur = kc & 1;
    if (kc < nt - 1) {
      size_t m0 = (size_t)(kc + 1) * 64;
      kr0 = *(const half8_t*)(ksrc + m0 * 64);
      kr1 = *(const half8_t*)(ksrc + m0 * 64 + 8);
      vr = *(const half8_t*)(vsrc + m0);
    }

    // ---- QK^T ----
    floatx4 sacc[4];
    #pragma unroll
    for (int t = 0; t < 4; ++t)
      #pragma unroll
      for (int r = 0; r < 4; ++r) sacc[t][r] = 0.f;
    #pragma unroll
    for (int t = 0; t < 4; ++t) {
      #pragma unroll
      for (int c = 0; c < 2; ++c) {
        half8_t ka = *(const half8_t*)&K_lds[cur][SWZ(t * 16 + q, c * 32 + g * 8)];
        sacc[t] = __builtin_amdgcn_mfma_f32_16x16x32_f16(ka, qv[c], sacc[t], 0, 0, 0);
      }
    }

    // ---- online softmax, defer-max (log2 domain) ----
    float tmax = fmaxf(fmaxf(sacc[0][0], sacc[0][1]), fmaxf(sacc[0][2], sacc[0][3]));
    #pragma unroll
    for (int t = 1; t < 4; ++t)
      tmax = fmaxf(tmax, fmaxf(fmaxf(sacc[t][0], sacc[t][1]), fmaxf(sacc[t][2], sacc[t][3])));
    tmax = fmaxf(tmax, __shfl_xor(tmax, 16));
    tmax = fmaxf(tmax, __shfl_xor(tmax, 32));
    if (__any(tmax > mrun + 8.f)) {
      float mnew = fmaxf(mrun, tmax);
      float corr = exp2fast(mrun - mnew);
      lrun *= corr;
      #pragma unroll
      for (int dt = 0; dt < 2; ++dt)
        #pragma unroll
        for (int r = 0; r < 4; ++r) oacc[dt][r] *= corr;
      mrun = mnew;
    }
    #pragma unroll
    for (int t = 0; t < 4; ++t)
      #pragma unroll
      for (int r = 0; r < 4; ++r) {
        float p = exp2fast(sacc[t][r] - mrun);
        sacc[t][r] = p;
        lrun += p;
      }

    // ---- P -> f16 -> per-wave LDS rows ----
    #pragma unroll
    for (int t = 0; t < 4; ++t) {
      half4_t ph;
      ph[0] = (_Float16)sacc[t][0];
      ph[1] = (_Float16)sacc[t][1];
      ph[2] = (_Float16)sacc[t][2];
      ph[3] = (_Float16)sacc[t][3];
      *(half4_t*)&P_lds[SWZ(w * 16 + q, t * 16 + g * 4)] = ph;
    }

    // ---- PV ----
    #pragma unroll
    for (int dt = 0; dt < 2; ++dt) {
      #pragma unroll
      for (int c = 0; c < 2; ++c) {
        half8_t va = *(const half8_t*)&V_lds[cur][SWZ(dt * 16 + q, c * 32 + g * 8)];
        half8_t pb = *(const half8_t*)&P_lds[SWZ(w * 16 + q, c * 32 + g * 8)];
        oacc[dt] = __builtin_amdgcn_mfma_f32_16x16x32_f16(va, pb, oacc[dt], 0, 0, 0);
      }
    }

    if (kc < nt - 1) {
      *(half8_t*)&K_lds[cur ^ 1][SWZ(kkey, koct)] = kr0;
      *(half8_t*)&K_lds[cur ^ 1][SWZ(kkey, koct + 8)] = kr1;
      *(half8_t*)&V_lds[cur ^ 1][SWZ(vd, voff)] = vr;
    }
    __syncthreads();
  }

  // deferred l reduction (cross g-groups)
  lrun += __shfl_xor(lrun, 16);
  lrun += __shfl_xor(lrun, 32);

  // ---- write partials ----
  size_t pbase = (((size_t)bh * 4 + seg) * 49 + qt);
  float* out_lds = (float*)&K_lds[0][0];   // 32*68*4 = 8704B
  #pragma unroll
  for (int dt = 0; dt < 2; ++dt)
    #pragma unroll
    for (int r = 0; r < 4; ++r) {
      int d = dt * 16 + g * 4 + r;
      out_lds[d * 68 + w * 16 + q] = oacc[dt][r];
    }
  if (lane < 16) ml2[pbase * 64 + w * 16 + lane] = make_float2(mrun, lrun);
  __syncthreads();
  {
    int d = tid >> 3;
    int i8 = (tid & 7) << 3;
    half8_t hv;
    #pragma unroll
    for (int j = 0; j < 8; ++j) hv[j] = (_Float16)out_lds[d * 68 + i8 + j];
    *(half8_t*)(Opart + pbase * 2048 + d * 64 + i8) = hv;
  }
}

// ---------------- merge 4 key-segments -> attno f16; fused channel sums ----------------
__global__ __launch_bounds__(256) void merge_kernel(const _Float16* __restrict__ Opart,
                                                    const float2* __restrict__ ml2,
                                                    _Float16* __restrict__ attno,
                                                    float* __restrict__ wx_raw) {
  int blk = blockIdx.x;          // 686: bh*49 + qt
  int qt = blk % 49, bh = blk / 49;
  int b = bh / 7, h = bh % 7;
  int tid = threadIdx.x, q = tid & 63, dg = tid >> 6;
  size_t p0 = (size_t)bh * 4 * 49 + qt;
  float2 s0 = ml2[(p0 + 0 * 49) * 64 + q];
  float2 s1 = ml2[(p0 + 1 * 49) * 64 + q];
  float2 s2 = ml2[(p0 + 2 * 49) * 64 + q];
  float2 s3 = ml2[(p0 + 3 * 49) * 64 + q];
  float m = fmaxf(fmaxf(s0.x, s1.x), fmaxf(s2.x, s3.x));
  float w0 = exp2fast(s0.x - m), w1 = exp2fast(s1.x - m);
  float w2 = exp2fast(s2.x - m), w3 = exp2fast(s3.x - m);
  float inv = 1.f / (s0.y * w0 + s1.y * w1 + s2.y * w2 + s3.y * w3);
  float osum[8];
  #pragma unroll
  for (int i = 0; i < 8; ++i) {
    int d = dg * 8 + i;
    float o = ((float)Opart[(p0 + 0 * 49) * 2048 + d * 64 + q] * w0 +
               (float)Opart[(p0 + 1 * 49) * 2048 + d * 64 + q] * w1 +
               (float)Opart[(p0 + 2 * 49) * 2048 + d * 64 + q] * w2 +
               (float)Opart[(p0 + 3 * 49) * 2048 + d * 64 + q] * w3) * inv;
    attno[((size_t)b * CCH + h * 32 + d) * NPIX + qt * 64 + q] = (_Float16)o;
    osum[i] = o;
  }
  #pragma unroll
  for (int i = 0; i < 8; ++i) {
    #pragma unroll
    for (int off = 32; off > 0; off >>= 1) osum[i] += __shfl_xor(osum[i], off);
  }
  if ((tid & 63) == 0) {
    #pragma unroll
    for (int i = 0; i < 8; ++i)
      atomicAdd(&wx_raw[b * CCH + h * 32 + dg * 8 + i], osum[i]);
  }
}

// ---------------- weff: wx = wo*sigmoid(mean); weff = wx . w3; beff = wx.b3 + bo ----------------
__global__ __launch_bounds__(256) void weff_kernel(const float* __restrict__ wx_raw,
                                                   const float* __restrict__ wo,
                                                   const float* __restrict__ w3,
                                                   const float* __restrict__ b3,
                                                   const float* __restrict__ bo,
                                                   float* __restrict__ weff,
                                                   float* __restrict__ beff) {
  __shared__ float wsh[CCH];
  __shared__ float scratch[8];
  int b = blockIdx.y;
  int t = threadIdx.x;
  if (t < CCH) {
    float mean = wx_raw[b * CCH + t] * (1.f / (float)NPIX);
    wsh[t] = wo[t] / (1.f + expf(-mean));
  }
  __syncthreads();
  int rem = blockIdx.x * 252 + t;
  if (t < 252 && rem < 2016) {
    float a0 = 0.f, a1 = 0.f, a2 = 0.f, a3 = 0.f;
    for (int c = 0; c < CCH; c += 4) {
      a0 = fmaf(wsh[c + 0], w3[(size_t)(c + 0) * 2016 + rem], a0);
      a1 = fmaf(wsh[c + 1], w3[(size_t)(c + 1) * 2016 + rem], a1);
      a2 = fmaf(wsh[c + 2], w3[(size_t)(c + 2) * 2016 + rem], a2);
      a3 = fmaf(wsh[c + 3], w3[(size_t)(c + 3) * 2016 + rem], a3);
    }
    weff[b * 2016 + rem] = (a0 + a1) + (a2 + a3);
  }
  if (blockIdx.x == 0) {
    float p = (t < CCH) ? wsh[t] * b3[t] : 0.f;
    float dummy = 0.f;
    blockReduce2(p, dummy, scratch);
    if (t == 0) beff[b] = p + bo[0];
  }
}

// ---------------- M_k(px) = sum_cp weff[cp][k] * attno_cp(px), 32 px/block ----------------
__global__ __launch_bounds__(256) void mk_kernel(const _Float16* __restrict__ attno,
                                                 const float* __restrict__ weff,
                                                 float* __restrict__ Mout) {
  __shared__ float wsh[2016];
  __shared__ float msh[8][9][32];
  int b = blockIdx.y, tile = blockIdx.x;   // 98 tiles of 32 px
  int tid = threadIdx.x;
  for (int i = tid; i < 2016; i += 256) wsh[i] = weff[b * 2016 + i];
  __syncthreads();
  int p = tid & 31, grp = tid >> 5;        // 8 channel-groups of 28
  int px = tile * 32 + p;
  const _Float16* A = attno + (size_t)b * CCH * NPIX + px;
  float m[9];
  #pragma unroll
  for (int k = 0; k < 9; ++k) m[k] = 0.f;
  for (int c = grp * 28; c < grp * 28 + 28; ++c) {
    float a = (float)A[(size_t)c * NPIX];
    const float* wp = &wsh[c * 9];
    #pragma unroll
    for (int k = 0; k < 9; ++k) m[k] = fmaf(a, wp[k], m[k]);
  }
  #pragma unroll
  for (int k = 0; k < 9; ++k) msh[grp][k][p] = m[k];
  __syncthreads();
  for (int i = tid; i < 288; i += 256) {
    int k = i >> 5, p2 = i & 31;
    float v = 0.f;
    #pragma unroll
    for (int gg = 0; gg < 8; ++gg) v += msh[gg][k][p2];
    Mout[((size_t)b * 9 + k) * NPIX + tile * 32 + p2] = v;
  }
}

// ---------------- final: out = sigmoid(sum_k M_k(shifted) + beff) ----------------
__global__ void final_kernel(const float* __restrict__ Mout, const float* __restrict__ beff,
                             float* __restrict__ dout) {
  int px = blockIdx.x * 256 + threadIdx.x;
  int b = blockIdx.y;
  if (px >= NPIX) return;
  int y = px / 56, x = px - y * 56;
  const float* Mb = Mout + (size_t)b * 9 * NPIX;
  float s = 0.f;
  #pragma unroll
  for (int ky = 0; ky < 3; ++ky) {
    int yy = y + ky - 1;
    if (yy < 0 || yy >= 56) continue;
    #pragma unroll
    for (int kx = 0; kx < 3; ++kx) {
      int xx = x + kx - 1;
      if (xx < 0 || xx >= 56) continue;
      s += Mb[(ky * 3 + kx) * NPIX + yy * 56 + xx];
    }
  }
  float v = s + beff[b];
  dout[b * NPIX + px] = 1.f / (1.f + expf(-v));
}

extern "C" void kernel_launch(void* const* d_in, const int* in_sizes, int n_in,
                              void* d_out, int out_size, void* d_ws, size_t ws_size,
                              hipStream_t stream) {
  (void)in_sizes; (void)n_in; (void)out_size; (void)ws_size;
  const float* D = (const float*)d_in[0];
  const float* wq = (const float*)d_in[1];
  const float* bq = (const float*)d_in[2];
  const float* wk = (const float*)d_in[3];
  const float* bk = (const float*)d_in[4];
  const float* wv = (const float*)d_in[5];
  const float* bv = (const float*)d_in[6];
  const float* gn_w = (const float*)d_in[7];
  const float* gn_b = (const float*)d_in[8];
  const float* lambda_init = (const float*)d_in[9];
  const float* lq1 = (const float*)d_in[10];
  const float* lk1 = (const float*)d_in[11];
  const float* lq2 = (const float*)d_in[12];
  const float* lk2 = (const float*)d_in[13];
  const float* w3 = (const float*)d_in[14];
  const float* b3 = (const float*)d_in[15];
  const float* wo = (const float*)d_in[16];
  const float* bo = (const float*)d_in[17];

  char* p = (char*)d_ws;
  _Float16* Dh = (_Float16*)p;          p += 2809856;
  _Float16* senh_h = (_Float16*)p;      p += 2809856;
  _Float16* Whq = (_Float16*)p;         p += 200704;
  _Float16* Whk = (_Float16*)p;         p += 200704;
  _Float16* Whv = (_Float16*)p;         p += 100352;
  _Float16* Qt = (_Float16*)p;          p += 5619712;
  _Float16* Kt = (_Float16*)p;          p += 5619712;
  _Float16* Vt = (_Float16*)p;          p += 2809856;
  _Float16* Opart = (_Float16*)p;       p += 11239424;   // 14*4*49*2048*2
  float2* ml2 = (float2*)p;             p += 1404928;    // 14*4*49*64*8
  _Float16* attno = (_Float16*)p;       p += 2809856;    // f16
  float* Mout = (float*)p;              p += 225792;
  float* wx_raw = (float*)p;            p += 1792;
  float* beff = (float*)p;              p += 64;
  float* lam = (float*)p;               p += 64;
  float* weff = (float*)p;              p += 16128;

  prep_kernel<<<448, 256, 0, stream>>>(D, gn_w, gn_b, senh_h, Dh,
                                       wq, wk, wv, Whq, Whk, Whv,
                                       lq1, lk1, lq2, lk2, lambda_init, lam);
  gemm_qkv_kernel<<<dim3(49, 18, 2), 256, 0, stream>>>(Whq, Whk, Whv, senh_h, Dh,
                                                       bq, bk, bv, Qt, Kt, Vt, lam);
  attn_part_kernel<<<2744, 256, 0, stream>>>(Qt, Kt, Vt, Opart, ml2, wx_raw);
  merge_kernel<<<686, 256, 0, stream>>>(Opart, ml2, attno, wx_raw);
  weff_kernel<<<dim3(8, 2), 256, 0, stream>>>(wx_raw, wo, w3, b3, bo, weff, beff);
  mk_kernel<<<dim3(98, 2), 256, 0, stream>>>(attno, weff, Mout);
  final_kernel<<<dim3(13, 2), 256, 0, stream>>>(Mout, beff, (float*)d_out);
}